// Round 6
// baseline (651.901 us; speedup 1.0000x reference)
//
#include <hip/hip_runtime.h>
#include <math.h>

#define N_NODES 50000
#define N_EDGES 600000
#define F_INPUT 128
#define HCDIM 256
#define NGRAPH 64
#define NCLS 3
#define MPAD 50048   // 391 * 128, GEMM M padded
#define SCAN_NB ((N_NODES + 255) / 256)   // 196
#define LOG2E 1.4426950408889634f
#define EDGE_BLOCKS 2048

typedef float f32x4 __attribute__((ext_vector_type(4)));
typedef _Float16 f16x8 __attribute__((ext_vector_type(8)));
typedef _Float16 f16x4 __attribute__((ext_vector_type(4)));
typedef _Float16 h2 __attribute__((ext_vector_type(2)));

__device__ __forceinline__ void gl_lds16(const void* g, void* l) {
    __builtin_amdgcn_global_load_lds(
        (const __attribute__((address_space(1))) unsigned int*)g,
        (__attribute__((address_space(3))) unsigned int*)l, 16, 0, 0);
}

__device__ __forceinline__ h2 bch2(unsigned int u) { return __builtin_bit_cast(h2, u); }

// packed leaky_relu(0.2): max(v,0) + 0.2*min(v,0)
__device__ __forceinline__ h2 lrelu2(h2 v) {
    const h2 z = {(_Float16)0.f, (_Float16)0.f};
    const h2 c = {(_Float16)0.2f, (_Float16)0.2f};
    h2 mx = __builtin_elementwise_max(v, z);
    h2 mn = __builtin_elementwise_min(v, z);
    return mx + mn * c;
}

// ============================ CSR build ============================
__global__ void hist_kernel(const int* __restrict__ ei, int* __restrict__ deg) {
    int i = blockIdx.x * 256 + threadIdx.x;
    int total = N_EDGES + N_NODES;
    if (i >= total) return;
    int d = (i < N_EDGES) ? ei[N_EDGES + i] : (i - N_EDGES);
    atomicAdd(&deg[d], 1);
}

__global__ void block_scan_kernel(const int* __restrict__ deg, int* __restrict__ rowptr,
                                  int* __restrict__ bsums) {
    __shared__ int wt[4];
    int b = blockIdx.x, t = threadIdx.x, lane = t & 63, wid = t >> 6;
    int i = b * 256 + t;
    int v = (i < N_NODES) ? deg[i] : 0;
    int x = v;
    #pragma unroll
    for (int off = 1; off < 64; off <<= 1) {
        int y = __shfl_up(x, off, 64);
        if (lane >= off) x += y;
    }
    if (lane == 63) wt[wid] = x;
    __syncthreads();
    if (t == 0) {
        int s = 0;
        #pragma unroll
        for (int j = 0; j < 4; ++j) { int tv = wt[j]; wt[j] = s; s += tv; }
        bsums[b] = s;
    }
    __syncthreads();
    if (i < N_NODES) rowptr[i] = wt[wid] + x - v;
}

__global__ void scan_bsums_kernel(int* __restrict__ bsums) {
    __shared__ int wt[4];
    int t = threadIdx.x, lane = t & 63, wid = t >> 6;
    int v = (t < SCAN_NB) ? bsums[t] : 0;
    int x = v;
    #pragma unroll
    for (int off = 1; off < 64; off <<= 1) {
        int y = __shfl_up(x, off, 64);
        if (lane >= off) x += y;
    }
    if (lane == 63) wt[wid] = x;
    __syncthreads();
    if (t == 0) {
        int s = 0;
        #pragma unroll
        for (int j = 0; j < 4; ++j) { int tv = wt[j]; wt[j] = s; s += tv; }
    }
    __syncthreads();
    if (t < SCAN_NB) bsums[t] = wt[wid] + x - v;
}

__global__ void add_off_kernel(int* __restrict__ rowptr, int* __restrict__ cursor,
                               const int* __restrict__ bsums) {
    int i = blockIdx.x * 256 + threadIdx.x;
    if (i < N_NODES) {
        int r = rowptr[i] + bsums[blockIdx.x];
        rowptr[i] = r;
        cursor[i] = r;
    }
    if (i == 0) rowptr[N_NODES] = N_EDGES + N_NODES;
}

__global__ void fill_kernel(const int* __restrict__ ei, int* __restrict__ cursor,
                            int* __restrict__ colx) {
    int i = blockIdx.x * 256 + threadIdx.x;
    int total = N_EDGES + N_NODES;
    if (i >= total) return;
    int s, d;
    if (i < N_EDGES) { s = ei[i]; d = ei[N_EDGES + i]; }
    else             { s = i - N_EDGES; d = s; }
    int pos = atomicAdd(&cursor[d], 1);
    colx[pos] = s;
}

// ============================ Input convert (layer 0) ============================
__global__ void split_x_kernel(const float* __restrict__ src, _Float16* __restrict__ A) {
    int idx = blockIdx.x * 256 + threadIdx.x;
    int base = idx * 4;
    if (base >= MPAD * F_INPUT) return;
    int row = base >> 7;
    float4 v = make_float4(0.f, 0.f, 0.f, 0.f);
    if (row < N_NODES) v = *(const float4*)&src[base];
    f16x4 o;
    o.x = (_Float16)v.x; o.y = (_Float16)v.y; o.z = (_Float16)v.z; o.w = (_Float16)v.w;
    *(f16x4*)&A[base] = o;
}

__global__ void zero_pad_kernel(_Float16* __restrict__ A) {
    int i = blockIdx.x * 256 + threadIdx.x;
    const int padh = (MPAD - N_NODES) * HCDIM;
    if (i * 4 < padh) {
        f16x4 z = {(_Float16)0.f, (_Float16)0.f, (_Float16)0.f, (_Float16)0.f};
        *(f16x4*)&A[(size_t)N_NODES * HCDIM + i * 4] = z;
    }
}

// ============================ Weight split: [Wl|Wr] -> n-major fp16 hi/lo ============================
__global__ void split_w_kernel(const float* __restrict__ Wl, const float* __restrict__ Wr,
                               _Float16* __restrict__ oh, _Float16* __restrict__ ol,
                               int K) {
    int t = blockIdx.x * 256 + threadIdx.x;
    if (t >= 512 * K) return;
    int n = t & 511, k = t >> 9;
    float w = (n < 256) ? Wl[k * 256 + n] : Wr[k * 256 + (n - 256)];
    _Float16 h = (_Float16)w;
    _Float16 l = (_Float16)(w - (float)h);
    oh[n * K + k] = h;
    ol[n * K + k] = l;
}

// ============================ fp16 2-term MFMA GEMM ============================
__global__ __launch_bounds__(256) void gemm_mfma(
    const _Float16* __restrict__ A,
    const _Float16* __restrict__ Bh, const _Float16* __restrict__ Bl,
    int K,
    const float* __restrict__ bl, const float* __restrict__ br,
    _Float16* __restrict__ xlh, _Float16* __restrict__ xrh)
{
    __shared__ _Float16 sA[128 * 32], sBh[128 * 32], sBl[128 * 32];
    int tid = threadIdx.x;
    int lane = tid & 63, wave = tid >> 6;
    int wm = wave >> 1, wn = wave & 1;
    int bx = blockIdx.x >> 2, by = blockIdx.x & 3;
    int row0 = bx * 128;
    int n0 = by * 128;
    int quad = lane >> 4, l16 = lane & 15;

    f32x4 acc[4][4];
    #pragma unroll
    for (int i = 0; i < 4; ++i)
        #pragma unroll
        for (int j = 0; j < 4; ++j)
            acc[i][j] = (f32x4){0.f, 0.f, 0.f, 0.f};

    for (int k0 = 0; k0 < K; k0 += 32) {
        __syncthreads();
        #pragma unroll
        for (int pass = 0; pass < 2; ++pass) {
            int c = tid + pass * 256;
            int r = c >> 2;
            int p = (c & 3) ^ ((r >> 1) & 3);
            size_t ga = (size_t)(row0 + r) * K + k0 + p * 8;
            size_t gb = (size_t)(n0 + r) * K + k0 + p * 8;
            gl_lds16(A + ga,  sA  + c * 8);
            gl_lds16(Bh + gb, sBh + c * 8);
            gl_lds16(Bl + gb, sBl + c * 8);
        }
        __syncthreads();

        f16x8 fa[4], fbh[4], fbl[4];
        #pragma unroll
        for (int i = 0; i < 4; ++i) {
            int rr = wm * 64 + i * 16 + l16;
            int sa = rr * 4 + (quad ^ ((rr >> 1) & 3));
            fa[i] = *(const f16x8*)&sA[sa * 8];
            int nn = wn * 64 + i * 16 + l16;
            int sb = nn * 4 + (quad ^ ((nn >> 1) & 3));
            fbh[i] = *(const f16x8*)&sBh[sb * 8];
            fbl[i] = *(const f16x8*)&sBl[sb * 8];
        }
        #pragma unroll
        for (int i = 0; i < 4; ++i)
            #pragma unroll
            for (int j = 0; j < 4; ++j) {
                acc[i][j] = __builtin_amdgcn_mfma_f32_16x16x32_f16(fa[i], fbh[j], acc[i][j], 0, 0, 0);
                acc[i][j] = __builtin_amdgcn_mfma_f32_16x16x32_f16(fa[i], fbl[j], acc[i][j], 0, 0, 0);
            }
    }

    _Float16* out; const float* bvec; int cb0;
    if (by < 2) { out = xlh; bvec = bl; cb0 = by * 128; }
    else        { out = xrh; bvec = br; cb0 = (by - 2) * 128; }
    #pragma unroll
    for (int j = 0; j < 4; ++j) {
        int col = cb0 + wn * 64 + j * 16 + l16;
        float bj = bvec[col];
        #pragma unroll
        for (int i = 0; i < 4; ++i) {
            int rbase = row0 + wm * 64 + i * 16 + quad * 4;
            #pragma unroll
            for (int r = 0; r < 4; ++r) {
                int row = rbase + r;
                if (row < N_NODES)
                    out[(size_t)row * HCDIM + col] = (_Float16)(acc[i][j][r] + bj);
            }
        }
    }
}

// ============================ Edge phase: 4-edge batched online softmax, 4-slot prefetch ============================
// Persistent grid-stride over nodes; one wave per node; lane l: head l>>4, channels (l&15)*4..+3.
// mode 0: write fp16 h (final layer, feeds pool). mode 1: write relu'd fp16 (next GEMM's A).
__global__ __launch_bounds__(256) void gat_edge(
    const _Float16* __restrict__ xlh, const _Float16* __restrict__ xrh,
    const float* __restrict__ att, const float* __restrict__ bias,
    const int* __restrict__ rowptr, const int* __restrict__ colx,
    _Float16* __restrict__ outh, _Float16* __restrict__ onext, int mode)
{
    int wave = threadIdx.x >> 6;
    int lane = threadIdx.x & 63;
    int base = lane * 4;

    float4 at4 = *(const float4*)&att[base];
    h2 ata = {(_Float16)at4.x, (_Float16)at4.y};
    h2 atb = {(_Float16)at4.z, (_Float16)at4.w};
    float4 b4 = *(const float4*)&bias[base];

    for (int node = blockIdx.x * 4 + wave; node < N_NODES; node += EDGE_BLOCKS * 4) {
        uint2 xrr = *(const uint2*)&xrh[(size_t)node * HCDIM + base];
        h2 xra = bch2(xrr.x), xrb = bch2(xrr.y);
        int e0 = rowptr[node], e1 = rowptr[node + 1];
        int elast = e1 - 1;                 // >= e0 (self-loop guarantees deg>=1)
        float m = -INFINITY, denom = 0.f;
        float4 acc = make_float4(0.f, 0.f, 0.f, 0.f);

        uint2 d[4];
        #pragma unroll
        for (int k = 0; k < 4; ++k) {
            int ee = e0 + k; ee = ee < e1 ? ee : elast;
            int s = colx[ee];
            d[k] = *(const uint2*)&xlh[(size_t)s * HCDIM + base];
        }

        for (int e = e0; e < e1; e += 4) {
            uint2 nd[4];
            #pragma unroll
            for (int k = 0; k < 4; ++k) {
                int ee = e + 4 + k; ee = ee < e1 ? ee : elast;
                int s = colx[ee];
                nd[k] = *(const uint2*)&xlh[(size_t)s * HCDIM + base];
            }

            h2 ax[4], bx[4];
            float p[4];
            #pragma unroll
            for (int k = 0; k < 4; ++k) {
                ax[k] = bch2(d[k].x); bx[k] = bch2(d[k].y);
                h2 la = lrelu2(ax[k] + xra);
                h2 lb = lrelu2(bx[k] + xrb);
                float pp = __builtin_amdgcn_fdot2(la, ata, 0.f, false);
                p[k] = __builtin_amdgcn_fdot2(lb, atb, pp, false);
            }
            #pragma unroll
            for (int off = 1; off <= 8; off <<= 1) {
                #pragma unroll
                for (int k = 0; k < 4; ++k) p[k] += __shfl_xor(p[k], off, 64);
            }
            #pragma unroll
            for (int k = 0; k < 4; ++k)
                p[k] = (e + k < e1) ? p[k] * LOG2E : -INFINITY;

            float mn = fmaxf(fmaxf(fmaxf(m, p[0]), fmaxf(p[1], p[2])), p[3]);
            float corr = exp2f(m - mn);      // exp2f(-inf-(-inf)) cannot occur: mn>=p[0]>-inf? p can be -inf only masked; first iter p[0] finite
            float w0 = exp2f(p[0] - mn), w1 = exp2f(p[1] - mn);
            float w2 = exp2f(p[2] - mn), w3 = exp2f(p[3] - mn);
            denom = denom * corr + ((w0 + w1) + (w2 + w3));
            acc.x = acc.x * corr + w0 * (float)ax[0].x + w1 * (float)ax[1].x
                                 + w2 * (float)ax[2].x + w3 * (float)ax[3].x;
            acc.y = acc.y * corr + w0 * (float)ax[0].y + w1 * (float)ax[1].y
                                 + w2 * (float)ax[2].y + w3 * (float)ax[3].y;
            acc.z = acc.z * corr + w0 * (float)bx[0].x + w1 * (float)bx[1].x
                                 + w2 * (float)bx[2].x + w3 * (float)bx[3].x;
            acc.w = acc.w * corr + w0 * (float)bx[0].y + w1 * (float)bx[1].y
                                 + w2 * (float)bx[2].y + w3 * (float)bx[3].y;
            m = mn;
            d[0] = nd[0]; d[1] = nd[1]; d[2] = nd[2]; d[3] = nd[3];
        }

        float inv = 1.f / denom;
        float ox = acc.x * inv + b4.x;
        float oy = acc.y * inv + b4.y;
        float oz = acc.z * inv + b4.z;
        float ow = acc.w * inv + b4.w;
        if (mode == 0) {
            f16x4 h;
            h.x = (_Float16)ox; h.y = (_Float16)oy;
            h.z = (_Float16)oz; h.w = (_Float16)ow;
            *(f16x4*)&outh[(size_t)node * HCDIM + base] = h;
        } else {
            f16x4 h;
            h.x = (_Float16)fmaxf(ox, 0.f); h.y = (_Float16)fmaxf(oy, 0.f);
            h.z = (_Float16)fmaxf(oz, 0.f); h.w = (_Float16)fmaxf(ow, 0.f);
            *(f16x4*)&onext[(size_t)node * HCDIM + base] = h;
        }
    }
}

// ============================ Pooling (fp16 input) ============================
__global__ void boundary_kernel(const int* __restrict__ batch, int* __restrict__ startg,
                                int* __restrict__ endg) {
    int i = blockIdx.x * 256 + threadIdx.x;
    if (i >= N_NODES) return;
    int g = batch[i];
    if (i == 0 || batch[i - 1] != g) startg[g] = i;
    if (i == N_NODES - 1 || batch[i + 1] != g) endg[g] = i + 1;
}

__global__ __launch_bounds__(256) void pool_kernel(
    const _Float16* __restrict__ h, const int* __restrict__ startg,
    const int* __restrict__ endg, float* __restrict__ p)
{
    __shared__ float4 sS[4][64];
    __shared__ float4 sM[4][64];
    int g = blockIdx.x;
    int lane = threadIdx.x & 63;
    int sub = threadIdx.x >> 6;
    int c0 = lane * 4;
    int s = startg[g], e = endg[g];
    float4 sum = make_float4(0.f, 0.f, 0.f, 0.f);
    float4 mx = make_float4(-INFINITY, -INFINITY, -INFINITY, -INFINITY);
    for (int i = s + sub; i < e; i += 4) {
        uint2 u = *(const uint2*)&h[(size_t)i * HCDIM + c0];
        h2 a = bch2(u.x), b = bch2(u.y);
        float4 v = make_float4((float)a.x, (float)a.y, (float)b.x, (float)b.y);
        sum.x += v.x; sum.y += v.y; sum.z += v.z; sum.w += v.w;
        mx.x = fmaxf(mx.x, v.x); mx.y = fmaxf(mx.y, v.y);
        mx.z = fmaxf(mx.z, v.z); mx.w = fmaxf(mx.w, v.w);
    }
    sS[sub][lane] = sum; sM[sub][lane] = mx;
    __syncthreads();
    if (sub == 0) {
        #pragma unroll
        for (int j = 1; j < 4; ++j) {
            float4 a = sS[j][lane], b = sM[j][lane];
            sum.x += a.x; sum.y += a.y; sum.z += a.z; sum.w += a.w;
            mx.x = fmaxf(mx.x, b.x); mx.y = fmaxf(mx.y, b.y);
            mx.z = fmaxf(mx.z, b.z); mx.w = fmaxf(mx.w, b.w);
        }
        int cnt = e - s;
        float inv = 1.f / fmaxf((float)cnt, 1.f);
        float4 o;
        o.x = sum.x * inv + mx.x; o.y = sum.y * inv + mx.y;
        o.z = sum.z * inv + mx.z; o.w = sum.w * inv + mx.w;
        *(float4*)&p[(size_t)g * HCDIM + c0] = o;
    }
}

// ============================ Head: logits + softmax ============================
__global__ void logits_kernel(const float* __restrict__ p, const float* __restrict__ Wout,
                              const float* __restrict__ bout, float* __restrict__ out)
{
    __shared__ float red[256];
    __shared__ float lg[NCLS];
    int g = blockIdx.x, t = threadIdx.x;
    float pv = p[g * HCDIM + t];
    for (int j = 0; j < NCLS; ++j) {
        red[t] = pv * Wout[t * NCLS + j];
        __syncthreads();
        for (int off = 128; off > 0; off >>= 1) {
            if (t < off) red[t] += red[t + off];
            __syncthreads();
        }
        if (t == 0) lg[j] = red[0] + bout[j];
        __syncthreads();
    }
    if (t == 0) {
        float mx = fmaxf(lg[0], fmaxf(lg[1], lg[2]));
        float e0 = __expf(lg[0] - mx), e1 = __expf(lg[1] - mx), e2 = __expf(lg[2] - mx);
        float inv = 1.f / (e0 + e1 + e2);
        out[g * NCLS + 0] = e0 * inv;
        out[g * NCLS + 1] = e1 * inv;
        out[g * NCLS + 2] = e2 * inv;
    }
}

// ============================ Orchestration ============================
extern "C" void kernel_launch(void* const* d_in, const int* in_sizes, int n_in,
                              void* d_out, int out_size, void* d_ws, size_t ws_size,
                              hipStream_t stream) {
    const float* x     = (const float*)d_in[0];
    const int*   ei    = (const int*)d_in[1];
    const int*   batch = (const int*)d_in[2];
    const float *Wl[3], *bl[3], *Wr[3], *br[3], *att[3], *bias[3];
    for (int li = 0; li < 3; ++li) {
        int b = 3 + li * 6;
        Wl[li]   = (const float*)d_in[b + 0];
        bl[li]   = (const float*)d_in[b + 1];
        Wr[li]   = (const float*)d_in[b + 2];
        br[li]   = (const float*)d_in[b + 3];
        att[li]  = (const float*)d_in[b + 4];
        bias[li] = (const float*)d_in[b + 5];
    }
    const float* Wout = (const float*)d_in[21];
    const float* bout = (const float*)d_in[22];
    float* out = (float*)d_out;

    size_t off = 0;
    char* wsb = (char*)d_ws;
    auto alloc = [&](size_t bytes) -> char* {
        char* ptr = wsb + off;
        off += (bytes + 255) & ~(size_t)255;
        return ptr;
    };
    int* rowptr  = (int*)alloc((N_NODES + 1) * sizeof(int));
    int* deg     = (int*)alloc(N_NODES * sizeof(int));
    int* cursor  = (int*)alloc(N_NODES * sizeof(int));
    int* bsums   = (int*)alloc(256 * sizeof(int));
    int* colx    = (int*)alloc((size_t)(N_EDGES + N_NODES) * sizeof(int));
    int* startg  = (int*)alloc(NGRAPH * sizeof(int));
    int* endg    = (int*)alloc(NGRAPH * sizeof(int));
    _Float16* Abuf = (_Float16*)alloc((size_t)MPAD * HCDIM * sizeof(_Float16));
    _Float16* Bth[3];
    _Float16* Btl[3];
    for (int li = 0; li < 3; ++li) {
        int K = (li == 0) ? F_INPUT : HCDIM;
        Bth[li] = (_Float16*)alloc((size_t)512 * K * sizeof(_Float16));
        Btl[li] = (_Float16*)alloc((size_t)512 * K * sizeof(_Float16));
    }
    _Float16* xlh  = (_Float16*)alloc((size_t)N_NODES * HCDIM * sizeof(_Float16));
    _Float16* xrh  = (_Float16*)alloc((size_t)N_NODES * HCDIM * sizeof(_Float16));
    _Float16* hbuf = (_Float16*)alloc((size_t)N_NODES * HCDIM * sizeof(_Float16));
    float* pbuf    = (float*)alloc((size_t)NGRAPH * HCDIM * sizeof(float));

    hipMemsetAsync(deg, 0, N_NODES * sizeof(int), stream);
    hipMemsetAsync(startg, 0, NGRAPH * sizeof(int), stream);
    hipMemsetAsync(endg, 0, NGRAPH * sizeof(int), stream);

    int tot = N_EDGES + N_NODES;
    hist_kernel<<<(tot + 255) / 256, 256, 0, stream>>>(ei, deg);
    block_scan_kernel<<<SCAN_NB, 256, 0, stream>>>(deg, rowptr, bsums);
    scan_bsums_kernel<<<1, 256, 0, stream>>>(bsums);
    add_off_kernel<<<SCAN_NB, 256, 0, stream>>>(rowptr, cursor, bsums);
    fill_kernel<<<(tot + 255) / 256, 256, 0, stream>>>(ei, cursor, colx);
    boundary_kernel<<<(N_NODES + 255) / 256, 256, 0, stream>>>(batch, startg, endg);

    split_x_kernel<<<(MPAD * F_INPUT / 4 + 255) / 256, 256, 0, stream>>>(x, Abuf);
    zero_pad_kernel<<<((MPAD - N_NODES) * HCDIM / 4 + 255) / 256, 256, 0, stream>>>(Abuf);
    for (int li = 0; li < 3; ++li) {
        int K = (li == 0) ? F_INPUT : HCDIM;
        split_w_kernel<<<(512 * K + 255) / 256, 256, 0, stream>>>(
            Wl[li], Wr[li], Bth[li], Btl[li], K);
    }

    for (int li = 0; li < 3; ++li) {
        int K = (li == 0) ? F_INPUT : HCDIM;
        gemm_mfma<<<(MPAD / 128) * 4, 256, 0, stream>>>(
            Abuf, Bth[li], Btl[li], K, bl[li], br[li], xlh, xrh);
        if (li < 2) {
            gat_edge<<<EDGE_BLOCKS, 256, 0, stream>>>(
                xlh, xrh, att[li], bias[li], rowptr, colx, nullptr, Abuf, 1);
        } else {
            gat_edge<<<EDGE_BLOCKS, 256, 0, stream>>>(
                xlh, xrh, att[li], bias[li], rowptr, colx, hbuf, nullptr, 0);
        }
    }

    pool_kernel<<<NGRAPH, 256, 0, stream>>>(hbuf, startg, endg, pbuf);
    logits_kernel<<<NGRAPH, 256, 0, stream>>>(pbuf, Wout, bout, out);
}

// Round 7
// 639.711 us; speedup vs baseline: 1.0191x; 1.0191x over previous
//
#include <hip/hip_runtime.h>
#include <math.h>

#define N_NODES 50000
#define N_EDGES 600000
#define F_INPUT 128
#define HCDIM 256
#define NGRAPH 64
#define NCLS 3
#define MPAD 50048   // 391 * 128, GEMM M padded
#define SCAN_NB ((N_NODES + 255) / 256)   // 196
#define LOG2E 1.4426950408889634f

// fused prep kernel block ranges
#define SPLITX_NB (MPAD * F_INPUT / 4 / 256)            // 6256
#define ZERO_NB   (((MPAD - N_NODES) * HCDIM / 4 + 255) / 256)  // 12
#define WPREP_NB  (512 * (F_INPUT + HCDIM + HCDIM) / 256)       // 1280
#define PREP_NB   (SPLITX_NB + ZERO_NB + WPREP_NB)
// fused hist+boundary ranges
#define HIST_NB   ((N_EDGES + N_NODES + 255) / 256)     // 2540
#define BND_NB    ((N_NODES + 255) / 256)               // 196

typedef float f32x4 __attribute__((ext_vector_type(4)));
typedef _Float16 f16x8 __attribute__((ext_vector_type(8)));
typedef _Float16 f16x4 __attribute__((ext_vector_type(4)));
typedef _Float16 h2 __attribute__((ext_vector_type(2)));

__device__ __forceinline__ void gl_lds16(const void* g, void* l) {
    __builtin_amdgcn_global_load_lds(
        (const __attribute__((address_space(1))) unsigned int*)g,
        (__attribute__((address_space(3))) unsigned int*)l, 16, 0, 0);
}

__device__ __forceinline__ h2 bch2(unsigned int u) { return __builtin_bit_cast(h2, u); }

// packed leaky_relu(0.2): max(v,0) + 0.2*min(v,0)
__device__ __forceinline__ h2 lrelu2(h2 v) {
    const h2 z = {(_Float16)0.f, (_Float16)0.f};
    const h2 c = {(_Float16)0.2f, (_Float16)0.2f};
    h2 mx = __builtin_elementwise_max(v, z);
    h2 mn = __builtin_elementwise_min(v, z);
    return mx + mn * c;
}

// ============================ hist + boundary (fused) ============================
__global__ void hist_boundary_kernel(const int* __restrict__ ei, int* __restrict__ deg,
                                     const int* __restrict__ batch,
                                     int* __restrict__ startg, int* __restrict__ endg) {
    int b = blockIdx.x;
    if (b < HIST_NB) {
        int i = b * 256 + threadIdx.x;
        int total = N_EDGES + N_NODES;
        if (i >= total) return;
        int d = (i < N_EDGES) ? ei[N_EDGES + i] : (i - N_EDGES);
        atomicAdd(&deg[d], 1);
    } else {
        int i = (b - HIST_NB) * 256 + threadIdx.x;
        if (i >= N_NODES) return;
        int g = batch[i];
        if (i == 0 || batch[i - 1] != g) startg[g] = i;
        if (i == N_NODES - 1 || batch[i + 1] != g) endg[g] = i + 1;
    }
}

// ============================ CSR scan ============================
__global__ void block_scan_kernel(const int* __restrict__ deg, int* __restrict__ rowptr,
                                  int* __restrict__ bsums) {
    __shared__ int wt[4];
    int b = blockIdx.x, t = threadIdx.x, lane = t & 63, wid = t >> 6;
    int i = b * 256 + t;
    int v = (i < N_NODES) ? deg[i] : 0;
    int x = v;
    #pragma unroll
    for (int off = 1; off < 64; off <<= 1) {
        int y = __shfl_up(x, off, 64);
        if (lane >= off) x += y;
    }
    if (lane == 63) wt[wid] = x;
    __syncthreads();
    if (t == 0) {
        int s = 0;
        #pragma unroll
        for (int j = 0; j < 4; ++j) { int tv = wt[j]; wt[j] = s; s += tv; }
        bsums[b] = s;
    }
    __syncthreads();
    if (i < N_NODES) rowptr[i] = wt[wid] + x - v;
}

__global__ void scan_bsums_kernel(int* __restrict__ bsums) {
    __shared__ int wt[4];
    int t = threadIdx.x, lane = t & 63, wid = t >> 6;
    int v = (t < SCAN_NB) ? bsums[t] : 0;
    int x = v;
    #pragma unroll
    for (int off = 1; off < 64; off <<= 1) {
        int y = __shfl_up(x, off, 64);
        if (lane >= off) x += y;
    }
    if (lane == 63) wt[wid] = x;
    __syncthreads();
    if (t == 0) {
        int s = 0;
        #pragma unroll
        for (int j = 0; j < 4; ++j) { int tv = wt[j]; wt[j] = s; s += tv; }
    }
    __syncthreads();
    if (t < SCAN_NB) bsums[t] = wt[wid] + x - v;
}

__global__ void add_off_kernel(int* __restrict__ rowptr, int* __restrict__ cursor,
                               const int* __restrict__ bsums) {
    int i = blockIdx.x * 256 + threadIdx.x;
    if (i < N_NODES) {
        int r = rowptr[i] + bsums[blockIdx.x];
        rowptr[i] = r;
        cursor[i] = r;
    }
    if (i == 0) rowptr[N_NODES] = N_EDGES + N_NODES;
}

// colx stores BYTE offsets into the fp16 feature matrix: s * HCDIM * 2
__global__ void fill_kernel(const int* __restrict__ ei, int* __restrict__ cursor,
                            int* __restrict__ colx) {
    int i = blockIdx.x * 256 + threadIdx.x;
    int total = N_EDGES + N_NODES;
    if (i >= total) return;
    int s, d;
    if (i < N_EDGES) { s = ei[i]; d = ei[N_EDGES + i]; }
    else             { s = i - N_EDGES; d = s; }
    int pos = atomicAdd(&cursor[d], 1);
    colx[pos] = s * (HCDIM * 2);
}

// ============================ Fused prep: x->fp16, pad zero, W->fp16 n-major ============================
__global__ void prep_kernel(const float* __restrict__ x, _Float16* __restrict__ A,
                            _Float16* __restrict__ Bt0, _Float16* __restrict__ Bt1,
                            _Float16* __restrict__ Bt2,
                            const float* __restrict__ Wl0, const float* __restrict__ Wr0,
                            const float* __restrict__ Wl1, const float* __restrict__ Wr1,
                            const float* __restrict__ Wl2, const float* __restrict__ Wr2) {
    int b = blockIdx.x;
    if (b < SPLITX_NB) {
        int base = (b * 256 + threadIdx.x) * 4;
        int row = base >> 7;
        float4 v = make_float4(0.f, 0.f, 0.f, 0.f);
        if (row < N_NODES) v = *(const float4*)&x[base];
        f16x4 o;
        o.x = (_Float16)v.x; o.y = (_Float16)v.y; o.z = (_Float16)v.z; o.w = (_Float16)v.w;
        *(f16x4*)&A[base] = o;
    } else if (b < SPLITX_NB + ZERO_NB) {
        int i = ((b - SPLITX_NB) * 256 + threadIdx.x) * 4;
        if (i < (MPAD - N_NODES) * HCDIM) {
            f16x4 z = {(_Float16)0.f, (_Float16)0.f, (_Float16)0.f, (_Float16)0.f};
            *(f16x4*)&A[(size_t)N_NODES * HCDIM + i] = z;
        }
    } else {
        int t = (b - SPLITX_NB - ZERO_NB) * 256 + threadIdx.x;
        const float* Wl; const float* Wr; _Float16* Bt; int K;
        if (t < 512 * F_INPUT)            { Wl = Wl0; Wr = Wr0; Bt = Bt0; K = F_INPUT; }
        else if (t < 512 * (F_INPUT + HCDIM)) { t -= 512 * F_INPUT; Wl = Wl1; Wr = Wr1; Bt = Bt1; K = HCDIM; }
        else                              { t -= 512 * (F_INPUT + HCDIM); Wl = Wl2; Wr = Wr2; Bt = Bt2; K = HCDIM; }
        int n = t & 511, k = t >> 9;
        float w = (n < 256) ? Wl[k * 256 + n] : Wr[k * 256 + (n - 256)];
        Bt[n * K + k] = (_Float16)w;
    }
}

// ============================ fp16 MFMA GEMM (single term) ============================
// C[MPAD,512] = A[MPAD,K] @ B[K,512]; 128x128 tile, BK=32, 4 waves, 4x4 16x16x32 f16 MFMA.
// XOR bank swizzle on the global-side k-chunk (LDS stays lane-contiguous for global_load_lds).
__global__ __launch_bounds__(256) void gemm_mfma(
    const _Float16* __restrict__ A, const _Float16* __restrict__ Bh,
    int K,
    const float* __restrict__ bl, const float* __restrict__ br,
    _Float16* __restrict__ xlh, _Float16* __restrict__ xrh)
{
    __shared__ _Float16 sA[128 * 32], sB[128 * 32];
    int tid = threadIdx.x;
    int lane = tid & 63, wave = tid >> 6;
    int wm = wave >> 1, wn = wave & 1;
    int bx = blockIdx.x >> 2, by = blockIdx.x & 3;
    int row0 = bx * 128;
    int n0 = by * 128;
    int quad = lane >> 4, l16 = lane & 15;

    f32x4 acc[4][4];
    #pragma unroll
    for (int i = 0; i < 4; ++i)
        #pragma unroll
        for (int j = 0; j < 4; ++j)
            acc[i][j] = (f32x4){0.f, 0.f, 0.f, 0.f};

    for (int k0 = 0; k0 < K; k0 += 32) {
        __syncthreads();
        #pragma unroll
        for (int pass = 0; pass < 2; ++pass) {
            int c = tid + pass * 256;
            int r = c >> 2;
            int p = (c & 3) ^ ((r >> 1) & 3);
            size_t ga = (size_t)(row0 + r) * K + k0 + p * 8;
            size_t gb = (size_t)(n0 + r) * K + k0 + p * 8;
            gl_lds16(A + ga, sA + c * 8);
            gl_lds16(Bh + gb, sB + c * 8);
        }
        __syncthreads();

        f16x8 fa[4], fb[4];
        #pragma unroll
        for (int i = 0; i < 4; ++i) {
            int rr = wm * 64 + i * 16 + l16;
            int sa = rr * 4 + (quad ^ ((rr >> 1) & 3));
            fa[i] = *(const f16x8*)&sA[sa * 8];
            int nn = wn * 64 + i * 16 + l16;
            int sb = nn * 4 + (quad ^ ((nn >> 1) & 3));
            fb[i] = *(const f16x8*)&sB[sb * 8];
        }
        #pragma unroll
        for (int i = 0; i < 4; ++i)
            #pragma unroll
            for (int j = 0; j < 4; ++j)
                acc[i][j] = __builtin_amdgcn_mfma_f32_16x16x32_f16(fa[i], fb[j], acc[i][j], 0, 0, 0);
    }

    _Float16* out; const float* bvec; int cb0;
    if (by < 2) { out = xlh; bvec = bl; cb0 = by * 128; }
    else        { out = xrh; bvec = br; cb0 = (by - 2) * 128; }
    #pragma unroll
    for (int j = 0; j < 4; ++j) {
        int col = cb0 + wn * 64 + j * 16 + l16;
        float bj = bvec[col];
        #pragma unroll
        for (int i = 0; i < 4; ++i) {
            int rbase = row0 + wm * 64 + i * 16 + quad * 4;
            #pragma unroll
            for (int r = 0; r < 4; ++r) {
                int row = rbase + r;
                if (row < N_NODES)
                    out[(size_t)row * HCDIM + col] = (_Float16)(acc[i][j][r] + bj);
            }
        }
    }
}

// ============================ Edge phase: 2-edge batched online softmax (R5 shape) ============================
// One wave per dst node; lane l: head l>>4, channels (l&15)*4..+3. colx holds byte offsets.
// mode 0: write fp16 h (feeds pool). mode 1: write relu'd fp16 (next GEMM's A).
__global__ __launch_bounds__(256) void gat_edge(
    const _Float16* __restrict__ xlh, const _Float16* __restrict__ xrh,
    const float* __restrict__ att, const float* __restrict__ bias,
    const int* __restrict__ rowptr, const int* __restrict__ colx,
    _Float16* __restrict__ outh, _Float16* __restrict__ onext, int mode)
{
    int wave = threadIdx.x >> 6;
    int lane = threadIdx.x & 63;
    int node = blockIdx.x * 4 + wave;
    if (node >= N_NODES) return;
    int lb = lane * 8;                       // byte offset within a row
    const char* xlb = (const char*)xlh;

    uint2 xrr = *(const uint2*)((const char*)xrh + (size_t)node * (HCDIM * 2) + lb);
    h2 xra = bch2(xrr.x), xrb = bch2(xrr.y);
    float4 at4 = *(const float4*)&att[lane * 4];
    h2 ata = {(_Float16)at4.x, (_Float16)at4.y};
    h2 atb = {(_Float16)at4.z, (_Float16)at4.w};

    int e0 = rowptr[node], e1 = rowptr[node + 1];
    float m = -INFINITY, denom = 0.f;
    float4 acc = make_float4(0.f, 0.f, 0.f, 0.f);

    int o0 = colx[e0];
    int o1 = colx[(e0 + 1 < e1) ? e0 + 1 : e0];
    uint2 d0 = *(const uint2*)(xlb + (size_t)(unsigned)o0 + lb);
    uint2 d1 = *(const uint2*)(xlb + (size_t)(unsigned)o1 + lb);

    for (int e = e0; e < e1; e += 2) {
        bool v1 = (e + 1 < e1);
        int i2 = (e + 2 < e1) ? e + 2 : e1 - 1;
        int i3 = (e + 3 < e1) ? e + 3 : e1 - 1;
        int on0 = colx[i2], on1 = colx[i3];
        uint2 nd0 = *(const uint2*)(xlb + (size_t)(unsigned)on0 + lb);
        uint2 nd1 = *(const uint2*)(xlb + (size_t)(unsigned)on1 + lb);

        h2 a0 = bch2(d0.x), b0 = bch2(d0.y);
        h2 a1 = bch2(d1.x), b1 = bch2(d1.y);

        h2 l0a = lrelu2(a0 + xra), l0b = lrelu2(b0 + xrb);
        h2 l1a = lrelu2(a1 + xra), l1b = lrelu2(b1 + xrb);
        float p0 = __builtin_amdgcn_fdot2(l0a, ata, 0.f, false);
        p0 = __builtin_amdgcn_fdot2(l0b, atb, p0, false);
        float p1 = __builtin_amdgcn_fdot2(l1a, ata, 0.f, false);
        p1 = __builtin_amdgcn_fdot2(l1b, atb, p1, false);

        p0 += __shfl_xor(p0, 1, 64);  p1 += __shfl_xor(p1, 1, 64);
        p0 += __shfl_xor(p0, 2, 64);  p1 += __shfl_xor(p1, 2, 64);
        p0 += __shfl_xor(p0, 4, 64);  p1 += __shfl_xor(p1, 4, 64);
        p0 += __shfl_xor(p0, 8, 64);  p1 += __shfl_xor(p1, 8, 64);
        p0 *= LOG2E;
        p1 = v1 ? p1 * LOG2E : -INFINITY;

        float mn = fmaxf(fmaxf(m, p0), p1);
        float corr = exp2f(m - mn);
        float w0 = exp2f(p0 - mn);
        float w1 = exp2f(p1 - mn);
        denom = denom * corr + w0 + w1;
        acc.x = acc.x * corr + w0 * (float)a0.x + w1 * (float)a1.x;
        acc.y = acc.y * corr + w0 * (float)a0.y + w1 * (float)a1.y;
        acc.z = acc.z * corr + w0 * (float)b0.x + w1 * (float)b1.x;
        acc.w = acc.w * corr + w0 * (float)b0.y + w1 * (float)b1.y;
        m = mn;
        d0 = nd0; d1 = nd1;
    }

    float inv = 1.f / denom;
    float4 b4 = *(const float4*)&bias[lane * 4];
    float ox = acc.x * inv + b4.x;
    float oy = acc.y * inv + b4.y;
    float oz = acc.z * inv + b4.z;
    float ow = acc.w * inv + b4.w;
    if (mode == 0) {
        f16x4 h;
        h.x = (_Float16)ox; h.y = (_Float16)oy;
        h.z = (_Float16)oz; h.w = (_Float16)ow;
        *(f16x4*)((char*)outh + (size_t)node * (HCDIM * 2) + lb) = h;
    } else {
        f16x4 h;
        h.x = (_Float16)fmaxf(ox, 0.f); h.y = (_Float16)fmaxf(oy, 0.f);
        h.z = (_Float16)fmaxf(oz, 0.f); h.w = (_Float16)fmaxf(ow, 0.f);
        *(f16x4*)((char*)onext + (size_t)node * (HCDIM * 2) + lb) = h;
    }
}

// ============================ Pooling (fp16 input) ============================
__global__ __launch_bounds__(256) void pool_kernel(
    const _Float16* __restrict__ h, const int* __restrict__ startg,
    const int* __restrict__ endg, float* __restrict__ p)
{
    __shared__ float4 sS[4][64];
    __shared__ float4 sM[4][64];
    int g = blockIdx.x;
    int lane = threadIdx.x & 63;
    int sub = threadIdx.x >> 6;
    int c0 = lane * 4;
    int s = startg[g], e = endg[g];
    float4 sum = make_float4(0.f, 0.f, 0.f, 0.f);
    float4 mx = make_float4(-INFINITY, -INFINITY, -INFINITY, -INFINITY);
    for (int i = s + sub; i < e; i += 4) {
        uint2 u = *(const uint2*)&h[(size_t)i * HCDIM + c0];
        h2 a = bch2(u.x), b = bch2(u.y);
        float4 v = make_float4((float)a.x, (float)a.y, (float)b.x, (float)b.y);
        sum.x += v.x; sum.y += v.y; sum.z += v.z; sum.w += v.w;
        mx.x = fmaxf(mx.x, v.x); mx.y = fmaxf(mx.y, v.y);
        mx.z = fmaxf(mx.z, v.z); mx.w = fmaxf(mx.w, v.w);
    }
    sS[sub][lane] = sum; sM[sub][lane] = mx;
    __syncthreads();
    if (sub == 0) {
        #pragma unroll
        for (int j = 1; j < 4; ++j) {
            float4 a = sS[j][lane], b = sM[j][lane];
            sum.x += a.x; sum.y += a.y; sum.z += a.z; sum.w += a.w;
            mx.x = fmaxf(mx.x, b.x); mx.y = fmaxf(mx.y, b.y);
            mx.z = fmaxf(mx.z, b.z); mx.w = fmaxf(mx.w, b.w);
        }
        int cnt = e - s;
        float inv = 1.f / fmaxf((float)cnt, 1.f);
        float4 o;
        o.x = sum.x * inv + mx.x; o.y = sum.y * inv + mx.y;
        o.z = sum.z * inv + mx.z; o.w = sum.w * inv + mx.w;
        *(float4*)&p[(size_t)g * HCDIM + c0] = o;
    }
}

// ============================ Head: logits + softmax ============================
__global__ void logits_kernel(const float* __restrict__ p, const float* __restrict__ Wout,
                              const float* __restrict__ bout, float* __restrict__ out)
{
    __shared__ float red[256];
    __shared__ float lg[NCLS];
    int g = blockIdx.x, t = threadIdx.x;
    float pv = p[g * HCDIM + t];
    for (int j = 0; j < NCLS; ++j) {
        red[t] = pv * Wout[t * NCLS + j];
        __syncthreads();
        for (int off = 128; off > 0; off >>= 1) {
            if (t < off) red[t] += red[t + off];
            __syncthreads();
        }
        if (t == 0) lg[j] = red[0] + bout[j];
        __syncthreads();
    }
    if (t == 0) {
        float mx = fmaxf(lg[0], fmaxf(lg[1], lg[2]));
        float e0 = __expf(lg[0] - mx), e1 = __expf(lg[1] - mx), e2 = __expf(lg[2] - mx);
        float inv = 1.f / (e0 + e1 + e2);
        out[g * NCLS + 0] = e0 * inv;
        out[g * NCLS + 1] = e1 * inv;
        out[g * NCLS + 2] = e2 * inv;
    }
}

// ============================ Orchestration ============================
extern "C" void kernel_launch(void* const* d_in, const int* in_sizes, int n_in,
                              void* d_out, int out_size, void* d_ws, size_t ws_size,
                              hipStream_t stream) {
    const float* x     = (const float*)d_in[0];
    const int*   ei    = (const int*)d_in[1];
    const int*   batch = (const int*)d_in[2];
    const float *Wl[3], *bl[3], *Wr[3], *br[3], *att[3], *bias[3];
    for (int li = 0; li < 3; ++li) {
        int b = 3 + li * 6;
        Wl[li]   = (const float*)d_in[b + 0];
        bl[li]   = (const float*)d_in[b + 1];
        Wr[li]   = (const float*)d_in[b + 2];
        br[li]   = (const float*)d_in[b + 3];
        att[li]  = (const float*)d_in[b + 4];
        bias[li] = (const float*)d_in[b + 5];
    }
    const float* Wout = (const float*)d_in[21];
    const float* bout = (const float*)d_in[22];
    float* out = (float*)d_out;

    size_t off = 0;
    char* wsb = (char*)d_ws;
    auto alloc = [&](size_t bytes) -> char* {
        char* ptr = wsb + off;
        off += (bytes + 255) & ~(size_t)255;
        return ptr;
    };
    int* rowptr  = (int*)alloc((N_NODES + 1) * sizeof(int));
    int* deg     = (int*)alloc(N_NODES * sizeof(int));
    int* cursor  = (int*)alloc(N_NODES * sizeof(int));
    int* bsums   = (int*)alloc(256 * sizeof(int));
    int* colx    = (int*)alloc((size_t)(N_EDGES + N_NODES) * sizeof(int));
    int* startg  = (int*)alloc(NGRAPH * sizeof(int));
    int* endg    = (int*)alloc(NGRAPH * sizeof(int));
    _Float16* Abuf = (_Float16*)alloc((size_t)MPAD * HCDIM * sizeof(_Float16));
    _Float16* Bt[3];
    for (int li = 0; li < 3; ++li) {
        int K = (li == 0) ? F_INPUT : HCDIM;
        Bt[li] = (_Float16*)alloc((size_t)512 * K * sizeof(_Float16));
    }
    _Float16* xlh  = (_Float16*)alloc((size_t)N_NODES * HCDIM * sizeof(_Float16));
    _Float16* xrh  = (_Float16*)alloc((size_t)N_NODES * HCDIM * sizeof(_Float16));
    _Float16* hbuf = (_Float16*)alloc((size_t)N_NODES * HCDIM * sizeof(_Float16));
    float* pbuf    = (float*)alloc((size_t)NGRAPH * HCDIM * sizeof(float));

    hipMemsetAsync(deg, 0, N_NODES * sizeof(int), stream);
    hipMemsetAsync(startg, 0, NGRAPH * sizeof(int), stream);
    hipMemsetAsync(endg, 0, NGRAPH * sizeof(int), stream);

    hist_boundary_kernel<<<HIST_NB + BND_NB, 256, 0, stream>>>(ei, deg, batch, startg, endg);
    block_scan_kernel<<<SCAN_NB, 256, 0, stream>>>(deg, rowptr, bsums);
    scan_bsums_kernel<<<1, 256, 0, stream>>>(bsums);
    add_off_kernel<<<SCAN_NB, 256, 0, stream>>>(rowptr, cursor, bsums);
    fill_kernel<<<(N_EDGES + N_NODES + 255) / 256, 256, 0, stream>>>(ei, cursor, colx);

    prep_kernel<<<PREP_NB, 256, 0, stream>>>(x, Abuf, Bt[0], Bt[1], Bt[2],
                                             Wl[0], Wr[0], Wl[1], Wr[1], Wl[2], Wr[2]);

    for (int li = 0; li < 3; ++li) {
        int K = (li == 0) ? F_INPUT : HCDIM;
        gemm_mfma<<<(MPAD / 128) * 4, 256, 0, stream>>>(
            Abuf, Bt[li], K, bl[li], br[li], xlh, xrh);
        if (li < 2) {
            gat_edge<<<N_NODES / 4, 256, 0, stream>>>(
                xlh, xrh, att[li], bias[li], rowptr, colx, nullptr, Abuf, 1);
        } else {
            gat_edge<<<N_NODES / 4, 256, 0, stream>>>(
                xlh, xrh, att[li], bias[li], rowptr, colx, hbuf, nullptr, 0);
        }
    }

    pool_kernel<<<NGRAPH, 256, 0, stream>>>(hbuf, startg, endg, pbuf);
    logits_kernel<<<NGRAPH, 256, 0, stream>>>(pbuf, Wout, bout, out);
}